// Round 1
// baseline (550.136 us; speedup 1.0000x reference)
//
#include <hip/hip_runtime.h>

#define NV 9
#define FIN 5
#define FHID 3
#define SPB 64            // samples per chunk (== block size, one sample/thread)
#define A_ELEMS (NV*NV)   // 81
#define H_ELEMS (NV*FIN)  // 45
#define A_CHUNK (SPB*A_ELEMS)  // 5184 floats = 20736 B = 20*1KB + 256B
#define H_CHUNK (SPB*H_ELEMS)  // 2880 floats = 11520 B = 11*1KB + 256B
#define PERSIST_BLOCKS 512     // 2 blocks/CU * 256 CU (LDS-limited residency)

// One wave moves 16 B/lane = 1024 B per instruction, global -> LDS, async.
// LDS dest is wave-uniform base + lane*16 (per-lane ptr must be linear in lane).
__device__ __forceinline__ void load_lds16(const float* g, float* l) {
    __builtin_amdgcn_global_load_lds(
        (const __attribute__((address_space(1))) unsigned int*)g,
        (__attribute__((address_space(3))) unsigned int*)l, 16, 0, 0);
}

// Stage one 64-sample chunk (A: 20.25 KB, h0: 11.25 KB) into an LDS buffer.
__device__ __forceinline__ void stage_chunk(const float* __restrict__ gA,
                                            const float* __restrict__ gH,
                                            float* bA, float* bH,
                                            int tid, int cnt)
{
    if (cnt == SPB) {
        // A: 20 full 1-KB wave transfers + 256 B tail (lanes 0..15)
#pragma unroll
        for (int j = 0; j < 20; j++)
            load_lds16(gA + j * 256 + tid * 4, bA + j * 256 + tid * 4);
        if (tid < 16)
            load_lds16(gA + 20 * 256 + tid * 4, bA + 20 * 256 + tid * 4);
        // h0: 11 full transfers + 256 B tail
#pragma unroll
        for (int j = 0; j < 11; j++)
            load_lds16(gH + j * 256 + tid * 4, bH + j * 256 + tid * 4);
        if (tid < 16)
            load_lds16(gH + 11 * 256 + tid * 4, bH + 11 * 256 + tid * 4);
    } else {
        // generic tail fallback (never hit at B=1e6); plain loads+ds_writes,
        // drained by the same vmcnt(0)/lgkm+barrier at the consumer.
        const int nA = cnt * A_ELEMS;
        for (int i = tid; i < nA; i += SPB) bA[i] = gA[i];
        const int nH = cnt * H_ELEMS;
        for (int i = tid; i < nH; i += SPB) bH[i] = gH[i];
    }
}

__global__ __launch_bounds__(64) void gcn_fused_kernel(
    const float* __restrict__ A, const float* __restrict__ h0,
    const float* __restrict__ W, const float* __restrict__ fc_w,
    const float* __restrict__ fc_b, float* __restrict__ out, int Btot)
{
    // Double-buffered chunk staging: 2*(20736+11520) = 64512 B (<= 64 KB/WG,
    // 2 blocks/CU -> 129 KB of the 160 KB LDS pool).
    __shared__ float sA[2][A_CHUNK];
    __shared__ float sH[2][H_CHUNK];

    const int tid = threadIdx.x;
    const int nChunks = (Btot + SPB - 1) / SPB;
    int c = blockIdx.x;
    if (c >= nChunks) return;
    const int stride = gridDim.x;

    // ---- tiny params (uniform -> scalar loads, cached; once per persistent block) ----
    float Wr[FIN * FHID];
#pragma unroll
    for (int i = 0; i < FIN * FHID; i++) Wr[i] = W[i];
    const float fw0 = fc_w[0], fw1 = fc_w[1], fw2 = fc_w[2];
    const float fb = fc_b[0];

    // ---- prologue: stage first chunk into buffer 0 ----
    {
        const long long base = (long long)c * SPB;
        const int cnt = (Btot - (int)base < SPB) ? (Btot - (int)base) : SPB;
        stage_chunk(A + base * A_ELEMS, h0 + base * H_ELEMS, sA[0], sH[0], tid, cnt);
    }
    int cur = 0;

    for (; c < nChunks; c += stride) {
        // RACE FIX: compiler does not model global_load_lds's LDS write —
        // force the drain before touching buffer[cur].
        asm volatile("s_waitcnt vmcnt(0)" ::: "memory");
        __syncthreads();

        // ---- prefetch chunk c+stride into the other buffer (2-deep pipeline):
        // its HBM latency hides under this chunk's compute. ----
        const int cn = c + stride;
        if (cn < nChunks) {
            const long long nb = (long long)cn * SPB;
            const int ncnt = (Btot - (int)nb < SPB) ? (Btot - (int)nb) : SPB;
            stage_chunk(A + nb * A_ELEMS, h0 + nb * H_ELEMS,
                        sA[cur ^ 1], sH[cur ^ 1], tid, ncnt);
        }

        const long long base = (long long)c * SPB;
        const int cnt = (Btot - (int)base < SPB) ? (Btot - (int)base) : SPB;

        if (tid < cnt) {
            const float* Ai = sA[cur] + tid * A_ELEMS;  // stride 81 words (odd) -> free 2-way alias
            const float* Hi = sH[cur] + tid * H_ELEMS;  // stride 45 words (odd)

            // Pull A into registers ONCE (81 ds_read), reuse for both passes:
            // cuts LDS reads 207 -> 126 per thread (compute must fit in the
            // DMA shadow at only 2 waves/CU).
            float a[A_ELEMS];
#pragma unroll
            for (int i = 0; i < A_ELEMS; i++) a[i] = Ai[i];

            // deg[j] = 1 + sum_i A[i][j]  (column sums of A + I)
            float deg[NV];
#pragma unroll
            for (int j = 0; j < NV; j++) deg[j] = 1.0f;
#pragma unroll
            for (int i = 0; i < NV; i++) {
#pragma unroll
                for (int j = 0; j < NV; j++) deg[j] += a[i * NV + j];
            }
            float dinv[NV];
#pragma unroll
            for (int j = 0; j < NV; j++) dinv[j] = 1.0f / sqrtf(deg[j]);

            // G[u][h] = dinv[u] * (h0[u,:] . W[:,h])
            float G[NV * FHID];
#pragma unroll
            for (int u = 0; u < NV; u++) {
                float hr[FIN];
#pragma unroll
                for (int f = 0; f < FIN; f++) hr[f] = Hi[u * FIN + f];
#pragma unroll
                for (int h = 0; h < FHID; h++) {
                    float acc = 0.0f;
#pragma unroll
                    for (int f = 0; f < FIN; f++) acc += hr[f] * Wr[f * FHID + h];
                    G[u * FHID + h] = dinv[u] * acc;
                }
            }

            // h2[h] = sum_v relu( dinv[v] * sum_u AI[v][u] * G[u][h] )
            float h2_0 = 0.0f, h2_1 = 0.0f, h2_2 = 0.0f;
#pragma unroll
            for (int v = 0; v < NV; v++) {
                float a0 = 0.0f, a1 = 0.0f, a2 = 0.0f;
#pragma unroll
                for (int u = 0; u < NV; u++) {
                    float aiv = a[v * NV + u] + ((u == v) ? 1.0f : 0.0f);
                    a0 += aiv * G[u * FHID + 0];
                    a1 += aiv * G[u * FHID + 1];
                    a2 += aiv * G[u * FHID + 2];
                }
                const float dv = dinv[v];
                a0 *= dv; a1 *= dv; a2 *= dv;
                h2_0 += fmaxf(a0, 0.0f);
                h2_1 += fmaxf(a1, 0.0f);
                h2_2 += fmaxf(a2, 0.0f);
            }

            out[base + tid] = h2_0 * fw0 + h2_1 * fw1 + h2_2 * fw2 + fb;
        }
        cur ^= 1;
    }
}

extern "C" void kernel_launch(void* const* d_in, const int* in_sizes, int n_in,
                              void* d_out, int out_size, void* d_ws, size_t ws_size,
                              hipStream_t stream) {
    const float* A    = (const float*)d_in[0];
    const float* h0   = (const float*)d_in[1];
    const float* W    = (const float*)d_in[2];
    const float* fc_w = (const float*)d_in[3];
    const float* fc_b = (const float*)d_in[4];
    float* out = (float*)d_out;

    const int Btot = in_sizes[0] / A_ELEMS;  // 1,000,000
    const int nChunks = (Btot + SPB - 1) / SPB;
    const int grid = nChunks < PERSIST_BLOCKS ? nChunks : PERSIST_BLOCKS;

    gcn_fused_kernel<<<grid, SPB, 0, stream>>>(A, h0, W, fc_w, fc_b, out, Btot);
}

// Round 3
// 546.292 us; speedup vs baseline: 1.0070x; 1.0070x over previous
//
#include <hip/hip_runtime.h>

#define NV 9
#define FIN 5
#define FHID 3
#define A_ELEMS (NV*NV)   // 81 floats = 324 B per sample
#define H_ELEMS (NV*FIN)  // 45 floats = 180 B per sample
#define TPB 256

// 16-byte load that is safe at 4-byte alignment (sample rows are only 4B-aligned:
// 324 % 16 != 0). __builtin_memcpy with align-4 still lowers to global_load_dwordx4
// on gfx9+ (unaligned-access-mode is on), without UB.
__device__ __forceinline__ float4 ld16(const float* p) {
    float4 v;
    __builtin_memcpy(&v, p, 16);
    return v;
}

// No LDS, no barriers, no DMA: each thread owns one sample and streams its own
// 324B + 180B through L1 as vectorized loads. Consecutive 16B loads of one thread
// are line-adjacent, so L1/MSHR merging keeps HBM traffic at exactly the useful
// bytes. Waves free-run -> latency hidden by TLP (VGPR-bound occupancy), the
// regime where the harness fill kernel reaches 6.6 TB/s.
__global__ __launch_bounds__(TPB, 2) void gcn_direct_kernel(
    const float* __restrict__ A, const float* __restrict__ h0,
    const float* __restrict__ W, const float* __restrict__ fc_w,
    const float* __restrict__ fc_b, float* __restrict__ out, int Btot)
{
    const int i = blockIdx.x * TPB + threadIdx.x;
    if (i >= Btot) return;

    const float* __restrict__ Ai = A  + (long long)i * A_ELEMS;
    const float* __restrict__ Hi = h0 + (long long)i * H_ELEMS;

    // ---- A row into registers: 20 x dwordx4 + 1 scalar (81 floats) ----
    float a[A_ELEMS];
#pragma unroll
    for (int j = 0; j < 20; j++) {
        float4 v = ld16(Ai + 4 * j);
        a[4*j+0] = v.x; a[4*j+1] = v.y; a[4*j+2] = v.z; a[4*j+3] = v.w;
    }
    a[80] = Ai[80];

    // ---- tiny params (uniform -> scalar loads, cached) ----
    float Wr[FIN * FHID];
#pragma unroll
    for (int k = 0; k < FIN * FHID; k++) Wr[k] = W[k];
    const float fw0 = fc_w[0], fw1 = fc_w[1], fw2 = fc_w[2];
    const float fb = fc_b[0];

    // ---- G[u][h] = h0[u,:] . W[:,h]  (computed BEFORE dinv so h0 regs die early;
    // dinv scaling is folded in afterwards) ----
    float G[NV * FHID];
#pragma unroll
    for (int u = 0; u < NV; u++) {
        float4 v = ld16(Hi + u * FIN);      // h[u][0..3]
        const float h4 = Hi[u * FIN + 4];   // h[u][4]
        const float hr[FIN] = {v.x, v.y, v.z, v.w, h4};
#pragma unroll
        for (int h = 0; h < FHID; h++) {
            float acc = 0.0f;
#pragma unroll
            for (int f = 0; f < FIN; f++) acc += hr[f] * Wr[f * FHID + h];
            G[u * FHID + h] = acc;
        }
    }

    // ---- deg[j] = 1 + sum_i A[i][j] (column sums of A + I), dinv = rsqrt ----
    float deg[NV];
#pragma unroll
    for (int j = 0; j < NV; j++) deg[j] = 1.0f;
#pragma unroll
    for (int r = 0; r < NV; r++) {
#pragma unroll
        for (int j = 0; j < NV; j++) deg[j] += a[r * NV + j];
    }
    float dinv[NV];
#pragma unroll
    for (int j = 0; j < NV; j++) dinv[j] = 1.0f / sqrtf(deg[j]);

    // fold dinv[u] into G
#pragma unroll
    for (int u = 0; u < NV; u++) {
#pragma unroll
        for (int h = 0; h < FHID; h++) G[u * FHID + h] *= dinv[u];
    }

    // ---- h2[h] = sum_v relu( dinv[v] * sum_u AI[v][u] * G[u][h] ) ----
    float h2_0 = 0.0f, h2_1 = 0.0f, h2_2 = 0.0f;
#pragma unroll
    for (int v = 0; v < NV; v++) {
        float a0 = 0.0f, a1 = 0.0f, a2 = 0.0f;
#pragma unroll
        for (int u = 0; u < NV; u++) {
            const float aiv = a[v * NV + u] + ((u == v) ? 1.0f : 0.0f);
            a0 += aiv * G[u * FHID + 0];
            a1 += aiv * G[u * FHID + 1];
            a2 += aiv * G[u * FHID + 2];
        }
        const float dv = dinv[v];
        h2_0 += fmaxf(a0 * dv, 0.0f);
        h2_1 += fmaxf(a1 * dv, 0.0f);
        h2_2 += fmaxf(a2 * dv, 0.0f);
    }

    out[i] = h2_0 * fw0 + h2_1 * fw1 + h2_2 * fw2 + fb;
}

extern "C" void kernel_launch(void* const* d_in, const int* in_sizes, int n_in,
                              void* d_out, int out_size, void* d_ws, size_t ws_size,
                              hipStream_t stream) {
    const float* A    = (const float*)d_in[0];
    const float* h0   = (const float*)d_in[1];
    const float* W    = (const float*)d_in[2];
    const float* fc_w = (const float*)d_in[3];
    const float* fc_b = (const float*)d_in[4];
    float* out = (float*)d_out;

    const int Btot = in_sizes[0] / A_ELEMS;  // 1,000,000
    const int grid = (Btot + TPB - 1) / TPB;

    gcn_direct_kernel<<<grid, TPB, 0, stream>>>(A, h0, W, fc_w, fc_b, out, Btot);
}